// Round 1
// baseline (1615.569 us; speedup 1.0000x reference)
//
#include <hip/hip_runtime.h>
#include <math.h>

// Problem constants
#define B_  2
#define N_  384
#define C_  256
#define H_  4
#define D_  64
#define NBH (B_*H_)            // 8
#define TSZ (NBH*N_*D_)        // 196608 floats per projected tensor [bh][n][d]
#define ESZ (NBH*N_*N_)        // 1179648 floats per exp-logit matrix [bh][i][j]
#define SCALE 0.125f           // D^-0.5

// ---------------------------------------------------------------------------
// Kernel 1: projection. Computes the 5 needed chunks {0,1,2,6,7} of x @ W^T,
// stored as proj[t][bh][n][d], t in {a,b,c,v1,v2}.
// M=768 rows (b*384+n), 1280 cols (t*256 + h*64 + d). 64x64 tiles, K=256.
// ---------------------------------------------------------------------------
__global__ __launch_bounds__(256) void proj_kernel(const float* __restrict__ x,
                                                   const float* __restrict__ W,
                                                   float* __restrict__ proj) {
    __shared__ float Xs[32][68];   // [k][m], pad 68 -> 16B-aligned rows, 4-way write conflict only
    __shared__ float Ws[32][68];
    const int tid = threadIdx.x;
    const int tx = tid & 15, ty = tid >> 4;
    const int m0 = blockIdx.x * 64;
    const int c0 = blockIdx.y * 64;
    const int t  = c0 >> 8;                              // tensor 0..4 (tiles never cross chunks)
    const int wbase = ((t >= 3) ? (t + 3) : t) * 256;    // chunk {0,1,2,6,7} * C

    float acc[4][4] = {{0.f}};
    for (int k0 = 0; k0 < 256; k0 += 32) {
        __syncthreads();
#pragma unroll
        for (int l = 0; l < 8; ++l) {
            const int idx = l * 256 + tid;
            const int mi = idx >> 5, kk = idx & 31;
            Xs[kk][mi] = x[(m0 + mi) * 256 + k0 + kk];
            const int rem = (c0 + mi) & 255;
            Ws[kk][mi] = W[(wbase + rem) * 256 + k0 + kk];
        }
        __syncthreads();
#pragma unroll
        for (int kk = 0; kk < 32; ++kk) {
            const float4 xf = *(const float4*)&Xs[kk][ty * 4];
            const float4 wf = *(const float4*)&Ws[kk][tx * 4];
            const float xa[4] = {xf.x, xf.y, xf.z, xf.w};
            const float wa[4] = {wf.x, wf.y, wf.z, wf.w};
#pragma unroll
            for (int q = 0; q < 4; ++q)
#pragma unroll
                for (int p = 0; p < 4; ++p)
                    acc[q][p] += xa[q] * wa[p];
        }
    }
#pragma unroll
    for (int q = 0; q < 4; ++q) {
        const int r = m0 + ty * 4 + q;
        const int b = r / N_;
        const int n = r - b * N_;
#pragma unroll
        for (int p = 0; p < 4; ++p) {
            const int rem = (c0 + tx * 4 + p) & 255;
            const int h = rem >> 6, d = rem & 63;
            proj[t * TSZ + ((b * H_ + h) * N_ + n) * D_ + d] = acc[q][p];
        }
    }
}

// ---------------------------------------------------------------------------
// Kernel 2: exp-logit matrices. q=0: eAB=exp(s*a·b^T), q=1: eCD=exp(s*b·c^T),
// q=2: eEF=exp(s*c·a^T). 64x64 tiles, K=64. Writes e[q][bh][i][j].
// ---------------------------------------------------------------------------
__global__ __launch_bounds__(256) void logits_kernel(const float* __restrict__ proj,
                                                     float* __restrict__ eout) {
    __shared__ float Xs[32][68];
    __shared__ float Ys[32][68];
    const int tid = threadIdx.x;
    const int tx = tid & 15, ty = tid >> 4;
    const int i0 = blockIdx.x * 64, j0 = blockIdx.y * 64;
    const int q  = blockIdx.z >> 3;
    const int bh = blockIdx.z & 7;
    const int xt = q;
    const int yt = (q == 2) ? 0 : (q + 1);
    const float* Xp = proj + xt * TSZ + bh * N_ * D_;
    const float* Yp = proj + yt * TSZ + bh * N_ * D_;
    float* Out = eout + q * ESZ + bh * N_ * N_;

    float acc[4][4] = {{0.f}};
    for (int k0 = 0; k0 < 64; k0 += 32) {
        __syncthreads();
#pragma unroll
        for (int l = 0; l < 8; ++l) {
            const int idx = l * 256 + tid;
            const int mi = idx >> 5, kk = idx & 31;
            Xs[kk][mi] = Xp[(i0 + mi) * 64 + k0 + kk];
            Ys[kk][mi] = Yp[(j0 + mi) * 64 + k0 + kk];
        }
        __syncthreads();
#pragma unroll
        for (int kk = 0; kk < 32; ++kk) {
            const float4 xf = *(const float4*)&Xs[kk][ty * 4];
            const float4 yf = *(const float4*)&Ys[kk][tx * 4];
            const float xa[4] = {xf.x, xf.y, xf.z, xf.w};
            const float ya[4] = {yf.x, yf.y, yf.z, yf.w};
#pragma unroll
            for (int qq = 0; qq < 4; ++qq)
#pragma unroll
                for (int p = 0; p < 4; ++p)
                    acc[qq][p] += xa[qq] * ya[p];
        }
    }
#pragma unroll
    for (int qq = 0; qq < 4; ++qq)
#pragma unroll
        for (int p = 0; p < 4; ++p)
            Out[(i0 + ty * 4 + qq) * N_ + j0 + tx * 4 + p] = expf(acc[qq][p] * SCALE);
}

// ---------------------------------------------------------------------------
// Kernel 3 (dominant): per (bh, d-slice dd, 64-row i-tile):
//   num[i,dd] = sum_j eAB[i,j]*v1[j,dd] * (sum_k eCD[i,k]*v2[k,dd]*eEF[j,k])
// dd==64 computes den (v1=v2=1). R tile (64x64) lives in registers per j-tile;
// never materialized globally. 59 GFLOP total across grid (6,65,8).
// ---------------------------------------------------------------------------
__global__ __launch_bounds__(256) void triplet_kernel(const float* __restrict__ eAB,
                                                      const float* __restrict__ eCD,
                                                      const float* __restrict__ eEF,
                                                      const float* __restrict__ v1,
                                                      const float* __restrict__ v2,
                                                      float* __restrict__ numout) {
    __shared__ float smem[2 * 32 * 68];          // Us/Es (k-tiles) or ABs (fold), reused
    __shared__ float v1s[64];
    float (*Us)[68]  = (float(*)[68])smem;       // [32][68]
    float (*Es)[68]  = (float(*)[68])(smem + 32 * 68);
    float (*ABs)[68] = (float(*)[68])smem;       // [64][68] == same 4352 floats

    const int tid = threadIdx.x;
    const int tx = tid & 15, ty = tid >> 4;
    const int i0 = blockIdx.x * 64;
    const int dd = blockIdx.y;                   // 0..64 (64 == denominator slice)
    const int bh = blockIdx.z;

    const float* eABp = eAB + bh * N_ * N_;
    const float* eCDp = eCD + bh * N_ * N_;
    const float* eEFp = eEF + bh * N_ * N_;
    const float* v1p  = v1 + bh * N_ * D_;
    const float* v2p  = v2 + bh * N_ * D_;

    float numacc[4] = {0.f, 0.f, 0.f, 0.f};

    for (int jt = 0; jt < 6; ++jt) {
        const int j0 = jt * 64;
        float acc[4][4] = {{0.f}};               // R tile fragment
        for (int kt = 0; kt < 12; ++kt) {
            const int k0 = kt * 32;
            __syncthreads();                     // protect prior LDS readers
#pragma unroll
            for (int l = 0; l < 8; ++l) {
                const int idx = l * 256 + tid;
                const int mi = idx >> 5, kk = idx & 31;
                const float v2v = (dd < 64) ? v2p[(k0 + kk) * 64 + dd] : 1.0f;
                Us[kk][mi] = eCDp[(i0 + mi) * N_ + k0 + kk] * v2v;
                Es[kk][mi] = eEFp[(j0 + mi) * N_ + k0 + kk];
            }
            __syncthreads();
#pragma unroll
            for (int kk = 0; kk < 32; ++kk) {
                const float4 uf = *(const float4*)&Us[kk][ty * 4];
                const float4 ef = *(const float4*)&Es[kk][tx * 4];
                const float ua[4] = {uf.x, uf.y, uf.z, uf.w};
                const float ea[4] = {ef.x, ef.y, ef.z, ef.w};
#pragma unroll
                for (int qq = 0; qq < 4; ++qq)
#pragma unroll
                    for (int p = 0; p < 4; ++p)
                        acc[qq][p] += ua[qq] * ea[p];
            }
        }
        // Fold: numacc[i] += sum_j eAB[i,j]*v1[j]*R[i,j] for this j-tile.
        __syncthreads();                         // inner-loop reads done; reuse smem as ABs
#pragma unroll
        for (int l = 0; l < 16; ++l) {
            const int idx = l * 256 + tid;
            const int mi = idx >> 6, jj = idx & 63;
            ABs[mi][jj] = eABp[(i0 + mi) * N_ + j0 + jj];
        }
        if (tid < 64) v1s[tid] = (dd < 64) ? v1p[(j0 + tid) * 64 + dd] : 1.0f;
        __syncthreads();
        const float4 wv = *(const float4*)&v1s[tx * 4];
        const float wa[4] = {wv.x, wv.y, wv.z, wv.w};
#pragma unroll
        for (int qq = 0; qq < 4; ++qq) {
            const float4 ab = *(const float4*)&ABs[ty * 4 + qq][tx * 4];
            numacc[qq] += ab.x * wa[0] * acc[qq][0]
                        + ab.y * wa[1] * acc[qq][1]
                        + ab.z * wa[2] * acc[qq][2]
                        + ab.w * wa[3] * acc[qq][3];
        }
    }
    // Reduce across the 16 tx lanes (lane = (ty%4)*16 + tx within the wave64).
#pragma unroll
    for (int qq = 0; qq < 4; ++qq) {
        float v = numacc[qq];
        v += __shfl_xor(v, 1);
        v += __shfl_xor(v, 2);
        v += __shfl_xor(v, 4);
        v += __shfl_xor(v, 8);
        numacc[qq] = v;
    }
    if (tx == 0) {
#pragma unroll
        for (int qq = 0; qq < 4; ++qq)
            numout[(bh * N_ + i0 + ty * 4 + qq) * 65 + dd] = numacc[qq];
    }
}

// ---------------------------------------------------------------------------
// Kernel 4: out[b,n,h*64+d] = num[bh,n,d] / den[bh,n]
// ---------------------------------------------------------------------------
__global__ __launch_bounds__(256) void finalize_kernel(const float* __restrict__ numw,
                                                       float* __restrict__ out) {
    const int o = blockIdx.x * 256 + threadIdx.x;      // [B][N][C] flat
    const int b = o / (N_ * C_);
    const int rem = o - b * (N_ * C_);
    const int n = rem >> 8;
    const int cc = rem & 255;
    const int h = cc >> 6, d = cc & 63;
    const float* base = numw + ((b * H_ + h) * N_ + n) * 65;
    out[o] = base[d] / base[64];
}

extern "C" void kernel_launch(void* const* d_in, const int* in_sizes, int n_in,
                              void* d_out, int out_size, void* d_ws, size_t ws_size,
                              hipStream_t stream) {
    const float* x = (const float*)d_in[0];
    const float* W = (const float*)d_in[1];
    float* ws   = (float*)d_ws;
    float* proj = ws;                       // 5*TSZ floats
    float* eAB  = ws + 5 * TSZ;             // ESZ
    float* eCD  = eAB + ESZ;                // ESZ
    float* eEF  = eCD + ESZ;                // ESZ
    float* numw = eEF + ESZ;                // NBH*N_*65
    // total: 4,721,664 floats ~= 18 MB of d_ws

    proj_kernel<<<dim3(12, 20), 256, 0, stream>>>(x, W, proj);
    logits_kernel<<<dim3(6, 6, 24), 256, 0, stream>>>(proj, eAB);
    triplet_kernel<<<dim3(6, 65, 8), 256, 0, stream>>>(eAB, eCD, eEF,
                                                       proj + 3 * TSZ, proj + 4 * TSZ, numw);
    finalize_kernel<<<dim3(768), 256, 0, stream>>>(numw, (float*)d_out);
}

// Round 2
// 251.206 us; speedup vs baseline: 6.4312x; 6.4312x over previous
//
#include <hip/hip_runtime.h>
#include <math.h>

#define B_  2
#define N_  384
#define C_  256
#define H_  4
#define D_  64
#define NBH (B_*H_)            // 8
#define TSZ (NBH*N_*D_)        // 196608 floats per projected tensor [bh][n][d]
#define ESZ (NBH*N_*N_)        // 1179648 elems per logit matrix [bh][i][j]
#define SCALE 0.125f           // D^-0.5
#define PIT 72                 // padded LDS pitch in f16 (144B) -> 2-way max bank alias

typedef _Float16 f16;
typedef f16  f16x8 __attribute__((ext_vector_type(8)));
typedef f16  f16x4 __attribute__((ext_vector_type(4)));
typedef float f32x4 __attribute__((ext_vector_type(4)));

// ---------------------------------------------------------------------------
// Kernel 1: projection (unchanged). proj[t][bh][n][d], t in {a,b,c,v1,v2}, f32.
// ---------------------------------------------------------------------------
__global__ __launch_bounds__(256) void proj_kernel(const float* __restrict__ x,
                                                   const float* __restrict__ W,
                                                   float* __restrict__ proj) {
    __shared__ float Xs[32][68];
    __shared__ float Ws[32][68];
    const int tid = threadIdx.x;
    const int tx = tid & 15, ty = tid >> 4;
    const int m0 = blockIdx.x * 64;
    const int c0 = blockIdx.y * 64;
    const int t  = c0 >> 8;
    const int wbase = ((t >= 3) ? (t + 3) : t) * 256;

    float acc[4][4] = {{0.f}};
    for (int k0 = 0; k0 < 256; k0 += 32) {
        __syncthreads();
#pragma unroll
        for (int l = 0; l < 8; ++l) {
            const int idx = l * 256 + tid;
            const int mi = idx >> 5, kk = idx & 31;
            Xs[kk][mi] = x[(m0 + mi) * 256 + k0 + kk];
            const int rem = (c0 + mi) & 255;
            Ws[kk][mi] = W[(wbase + rem) * 256 + k0 + kk];
        }
        __syncthreads();
#pragma unroll
        for (int kk = 0; kk < 32; ++kk) {
            const float4 xf = *(const float4*)&Xs[kk][ty * 4];
            const float4 wf = *(const float4*)&Ws[kk][tx * 4];
            const float xa[4] = {xf.x, xf.y, xf.z, xf.w};
            const float wa[4] = {wf.x, wf.y, wf.z, wf.w};
#pragma unroll
            for (int q = 0; q < 4; ++q)
#pragma unroll
                for (int p = 0; p < 4; ++p)
                    acc[q][p] += xa[q] * wa[p];
        }
    }
#pragma unroll
    for (int q = 0; q < 4; ++q) {
        const int r = m0 + ty * 4 + q;
        const int b = r / N_;
        const int n = r - b * N_;
#pragma unroll
        for (int p = 0; p < 4; ++p) {
            const int rem = (c0 + tx * 4 + p) & 255;
            const int h = rem >> 6, d = rem & 63;
            proj[t * TSZ + ((b * H_ + h) * N_ + n) * D_ + d] = acc[q][p];
        }
    }
}

// ---------------------------------------------------------------------------
// Kernel 2: exp-logit matrices, mixed-dtype outputs.
//  q=0: eABt16[bh][j][i] = f16(exp(s a_i . b_j))   (transposed, for the fold)
//  q=1: eCD  [bh][i][k] f32                        (kept f32: U built precisely)
//  q=2: eEF16[bh][j][k] f16                        (MFMA B operand)
// ---------------------------------------------------------------------------
__global__ __launch_bounds__(256) void logits_kernel(const float* __restrict__ proj,
                                                     f16* __restrict__ eabt16,
                                                     float* __restrict__ ecd,
                                                     f16* __restrict__ eef16) {
    __shared__ float Xs[32][68];
    __shared__ float Ys[32][68];
    const int tid = threadIdx.x;
    const int tx = tid & 15, ty = tid >> 4;
    const int i0 = blockIdx.x * 64, j0 = blockIdx.y * 64;
    const int q  = blockIdx.z >> 3;
    const int bh = blockIdx.z & 7;
    const int xt = q;
    const int yt = (q == 2) ? 0 : (q + 1);
    const float* Xp = proj + xt * TSZ + bh * N_ * D_;
    const float* Yp = proj + yt * TSZ + bh * N_ * D_;

    float acc[4][4] = {{0.f}};
    for (int k0 = 0; k0 < 64; k0 += 32) {
        __syncthreads();
#pragma unroll
        for (int l = 0; l < 8; ++l) {
            const int idx = l * 256 + tid;
            const int mi = idx >> 5, kk = idx & 31;
            Xs[kk][mi] = Xp[(i0 + mi) * 64 + k0 + kk];
            Ys[kk][mi] = Yp[(j0 + mi) * 64 + k0 + kk];
        }
        __syncthreads();
#pragma unroll
        for (int kk = 0; kk < 32; ++kk) {
            const float4 xf = *(const float4*)&Xs[kk][ty * 4];
            const float4 yf = *(const float4*)&Ys[kk][tx * 4];
            const float xa[4] = {xf.x, xf.y, xf.z, xf.w};
            const float ya[4] = {yf.x, yf.y, yf.z, yf.w};
#pragma unroll
            for (int qq = 0; qq < 4; ++qq)
#pragma unroll
                for (int p = 0; p < 4; ++p)
                    acc[qq][p] += xa[qq] * ya[p];
        }
    }
#pragma unroll
    for (int qq = 0; qq < 4; ++qq)
#pragma unroll
        for (int p = 0; p < 4; ++p) {
            const float e = expf(acc[qq][p] * SCALE);
            const int ii = i0 + ty * 4 + qq;
            const int jj = j0 + tx * 4 + p;
            if (q == 0)      eabt16[(size_t)bh * N_ * N_ + jj * N_ + ii] = (f16)e;
            else if (q == 1) ecd   [(size_t)bh * N_ * N_ + ii * N_ + jj] = e;
            else             eef16 [(size_t)bh * N_ * N_ + ii * N_ + jj] = (f16)e;
        }
}

// ---------------------------------------------------------------------------
// Kernel 3 (dominant), MFMA f16. Block: (i-tile 64, d-group of 4, bh).
// Wave w owns d = dg*4+w (>=64 -> denominator slice, v1=v2=1).
// kt-outer (K=64): build U16 (4 d-slices) in LDS, load A-frags to regs;
// jt-inner: stage eEF16/eABt16 tiles, 32 MFMAs (16 tiles x K64), fold the
// partial R immediately (fold is linear in R): numacc += eABt*v1*R.
// ---------------------------------------------------------------------------
__global__ __launch_bounds__(256) void triplet_mfma_kernel(
        const f16*  __restrict__ eabt,   // [bh][j][i]
        const float* __restrict__ ecd,   // [bh][i][k]
        const f16*  __restrict__ eef,    // [bh][j][k]
        const float* __restrict__ v1,    // [bh][n][64]
        const float* __restrict__ v2,    // [bh][n][64]
        float* __restrict__ numout) {    // [bh][i][68]
    __shared__ __align__(16) unsigned char smem_raw[62464];
    f16*   us   = (f16*)smem_raw;                    // 4 * 64*PIT f16   = 36864 B
    f16*   es   = us + 4 * 64 * PIT;                 // 64*PIT f16       =  9216 B
    f16*   abts = es + 64 * PIT;                     // 64*PIT f16       =  9216 B
    float* v1s  = (float*)(smem_raw + 55296);        // 384*4 f32        =  6144 B
    float* v2k  = (float*)(smem_raw + 61440);        // 4*64 f32         =  1024 B

    const int tid  = threadIdx.x;
    const int lane = tid & 63;
    const int w    = tid >> 6;        // wave id = d slot
    const int quad = lane >> 4;
    const int lr   = lane & 15;
    const int i0 = blockIdx.x * 64;
    const int dg = blockIdx.y;        // 0..16
    const int bh = blockIdx.z;
    const int dd = dg * 4 + w;        // 0..67 (>=64: denominator)

    const f16*   eabtb = eabt + (size_t)bh * N_ * N_;
    const float* ecdb  = ecd  + (size_t)bh * N_ * N_;
    const f16*   eefb  = eef  + (size_t)bh * N_ * N_;
    const float* v1b   = v1 + (size_t)bh * N_ * D_;
    const float* v2b   = v2 + (size_t)bh * N_ * D_;

    // stage v1 columns for the 4 d-slots: v1s[j*4 + c]
#pragma unroll
    for (int it = 0; it < 6; ++it) {
        const int id = it * 256 + tid;          // 0..1535
        const int j = id >> 2, c = id & 3;
        const int d2 = dg * 4 + c;
        v1s[id] = (d2 < 64) ? v1b[j * 64 + d2] : 1.0f;
    }

    float numacc[16];
#pragma unroll
    for (int r = 0; r < 16; ++r) numacc[r] = 0.f;

    for (int kt = 0; kt < 6; ++kt) {
        const int k0 = kt * 64;
        __syncthreads();                 // prior readers of us/v2k done
        // stage v2 chunk: v2k[c*64 + k]
        {
            const int c = tid >> 6, k = tid & 63;
            const int d2 = dg * 4 + c;
            v2k[c * 64 + k] = (d2 < 64) ? v2b[(k0 + k) * 64 + d2] : 1.0f;
        }
        __syncthreads();
        // build U16[d][64i][PIT k] = f16(eCD * v2col)
#pragma unroll
        for (int it = 0; it < 4; ++it) {
            const int row  = it * 16 + (tid >> 4);
            const int kcol = (tid & 15) * 4;
            const float4 c4 = *(const float4*)&ecdb[(i0 + row) * N_ + k0 + kcol];
#pragma unroll
            for (int d = 0; d < 4; ++d) {
                const float4 w4 = *(const float4*)&v2k[d * 64 + kcol];
                union { f16 h[4]; unsigned long long u; } pk;
                pk.h[0] = (f16)(c4.x * w4.x);
                pk.h[1] = (f16)(c4.y * w4.y);
                pk.h[2] = (f16)(c4.z * w4.z);
                pk.h[3] = (f16)(c4.w * w4.w);
                *(unsigned long long*)(us + d * 64 * PIT + row * PIT + kcol) = pk.u;
            }
        }
        __syncthreads();
        // A-frags for this wave's d, all 4 i-subtiles x 2 k-halves
        f16x8 af[4][2];
#pragma unroll
        for (int isub = 0; isub < 4; ++isub)
#pragma unroll
            for (int ks = 0; ks < 2; ++ks)
                af[isub][ks] = *(const f16x8*)(us + w * 64 * PIT +
                                               (isub * 16 + lr) * PIT + (ks * 4 + quad) * 8);

        for (int jt = 0; jt < 6; ++jt) {
            const int j0 = jt * 64;
            __syncthreads();             // prior readers of es/abts done
#pragma unroll
            for (int it = 0; it < 2; ++it) {
                const int row = it * 32 + (tid >> 3);
                const int blk = tid & 7;
                *(uint4*)(es   + row * PIT + blk * 8) =
                    *(const uint4*)(eefb  + (j0 + row) * N_ + k0 + blk * 8);
                *(uint4*)(abts + row * PIT + blk * 8) =
                    *(const uint4*)(eabtb + (j0 + row) * N_ + i0 + blk * 8);
            }
            __syncthreads();
            // B-frags (shared across the 4 i-subtiles)
            f16x8 bf[4][2];
#pragma unroll
            for (int js = 0; js < 4; ++js)
#pragma unroll
                for (int ks = 0; ks < 2; ++ks)
                    bf[js][ks] = *(const f16x8*)(es + (js * 16 + lr) * PIT + (ks * 4 + quad) * 8);
            // MFMA + immediate fold of the partial R tile
#pragma unroll
            for (int js = 0; js < 4; ++js) {
                const float v1v = v1s[(j0 + js * 16 + lr) * 4 + w];
#pragma unroll
                for (int isub = 0; isub < 4; ++isub) {
                    f32x4 t = {0.f, 0.f, 0.f, 0.f};
                    t = __builtin_amdgcn_mfma_f32_16x16x32_f16(af[isub][0], bf[js][0], t, 0, 0, 0);
                    t = __builtin_amdgcn_mfma_f32_16x16x32_f16(af[isub][1], bf[js][1], t, 0, 0, 0);
                    const f16x4 ab = *(const f16x4*)(abts + (js * 16 + lr) * PIT +
                                                     isub * 16 + quad * 4);
#pragma unroll
                    for (int q = 0; q < 4; ++q)
                        numacc[isub * 4 + q] += (float)ab[q] * (v1v * t[q]);
                }
            }
        }
    }
    // reduce the j-residues (low 4 lane bits) and write
#pragma unroll
    for (int r = 0; r < 16; ++r) {
        float v = numacc[r];
        v += __shfl_xor(v, 1);
        v += __shfl_xor(v, 2);
        v += __shfl_xor(v, 4);
        v += __shfl_xor(v, 8);
        numacc[r] = v;
    }
    if (lr == 0) {
#pragma unroll
        for (int r = 0; r < 16; ++r) {
            const int i = (r >> 2) * 16 + quad * 4 + (r & 3);
            numout[((size_t)bh * N_ + i0 + i) * 68 + dd] = numacc[r];
        }
    }
}

// ---------------------------------------------------------------------------
// Kernel 4: out[b,n,h*64+d] = num[bh,n,d] / den[bh,n]  (den at slot 64)
// ---------------------------------------------------------------------------
__global__ __launch_bounds__(256) void finalize_kernel(const float* __restrict__ numw,
                                                       float* __restrict__ out) {
    const int o = blockIdx.x * 256 + threadIdx.x;
    const int b = o / (N_ * C_);
    const int rem = o - b * (N_ * C_);
    const int n = rem >> 8;
    const int cc = rem & 255;
    const int h = cc >> 6, d = cc & 63;
    const float* base = numw + (((size_t)b * H_ + h) * N_ + n) * 68;
    out[o] = base[d] / base[64];
}

extern "C" void kernel_launch(void* const* d_in, const int* in_sizes, int n_in,
                              void* d_out, int out_size, void* d_ws, size_t ws_size,
                              hipStream_t stream) {
    const float* x = (const float*)d_in[0];
    const float* W = (const float*)d_in[1];
    float* ws    = (float*)d_ws;
    float* proj  = ws;                         // 5*TSZ f32
    float* ecd   = ws + 5 * TSZ;               // ESZ f32
    float* numw  = ecd + ESZ;                  // 8*384*68 f32 = 208896
    f16*   eabt  = (f16*)(numw + NBH * N_ * 68);  // ESZ f16
    f16*   eef   = eabt + ESZ;                 // ESZ f16
    // total ~ 3.93 + 4.72 + 0.84 + 2.36 + 2.36 MB ~= 14.2 MB of d_ws

    proj_kernel<<<dim3(12, 20), 256, 0, stream>>>(x, W, proj);
    logits_kernel<<<dim3(6, 6, 24), 256, 0, stream>>>(proj, eabt, ecd, eef);
    triplet_mfma_kernel<<<dim3(6, 17, 8), 256, 0, stream>>>(
        eabt, ecd, eef, proj + 3 * TSZ, proj + 4 * TSZ, numw);
    finalize_kernel<<<dim3(768), 256, 0, stream>>>(numw, (float*)d_out);
}